// Round 6
// baseline (1224.851 us; speedup 1.0000x reference)
//
#include <hip/hip_runtime.h>
#include <hip/hip_fp16.h>

typedef _Float16 half_t;
typedef _Float16 half2_t __attribute__((ext_vector_type(2)));
typedef _Float16 f16x8 __attribute__((ext_vector_type(8)));
typedef float f32x4 __attribute__((ext_vector_type(4)));
typedef unsigned int u32;

// B=256, T=500, I=H=256, O=128, M=B*T=128000
#define MROWS 128000
#define KDIM 256
#define TANH_SCALE 2.8853900817779268f   // 2*log2(e): folded into Whh, Wih, biases

// ---------------- prep: convert weights to f16 layouts, fold biases ----------
__global__ __launch_bounds__(256) void prep_kernel(
    const float* __restrict__ Wih0, const float* __restrict__ Whh0,
    const float* __restrict__ bih0, const float* __restrict__ bhh0,
    const float* __restrict__ Wih1, const float* __restrict__ Whh1,
    const float* __restrict__ bih1, const float* __restrict__ bhh1,
    const float* __restrict__ fcW,  const float* __restrict__ fcb,
    half_t* __restrict__ Wh0, half_t* __restrict__ Wh1, half_t* __restrict__ fcWh,
    half_t* __restrict__ Whh0h, half_t* __restrict__ Whh1h,
    float* __restrict__ bias0, float* __restrict__ bias1, float* __restrict__ bias2)
{
    const float c = TANH_SCALE;
    int e = blockIdx.x * 256 + threadIdx.x;   // 0..65535
    Wh0[e] = (half_t)(Wih0[e] * c);           // scaled: xp0 arrives pre-multiplied
    Wh1[e] = (half_t)(Wih1[e] * c);           // scaled: used directly by fused scan
    Whh0h[e] = (half_t)(Whh0[e] * c);
    Whh1h[e] = (half_t)(Whh1[e] * c);
    if (e < 32768) fcWh[e] = (half_t)fcW[e];  // FC unscaled
    if (e < 256) { bias0[e] = (bih0[e] + bhh0[e]) * c; bias1[e] = (bih1[e] + bhh1[e]) * c; }
    if (e < 128) { bias2[e] = fcb[e]; }
}

// ---------------- GEMM: C[M,NT] = A[M,256] * W[NT,256]^T + bias (f16 MFMA) ---
template<typename AT, typename OT, int NT, bool SIG>
__global__ __launch_bounds__(512) void gemm_bt(
    const AT* __restrict__ A, const half_t* __restrict__ W,
    const float* __restrict__ bias, OT* __restrict__ C)
{
    constexpr int K = KDIM;
    __shared__ __align__(16) half_t As[128][72];   // +8 pad: 2-way bank alias only
    __shared__ __align__(16) half_t Ws[NT][72];
    __shared__ float bs[NT];
    const int tid  = threadIdx.x;
    const int row0 = blockIdx.x * 128;
    if (tid < NT) bs[tid] = bias[tid];
    constexpr int NFRAG = NT / 64;                 // 4 (NT=256) or 2 (NT=128)
    f32x4 acc[4][NFRAG] = {};
    const int lane = tid & 63;
    const int wid  = tid >> 6;                     // 8 waves: 2 (rows) x 4 (cols)
    const int wr = wid >> 2, wc = wid & 3;

    for (int kt = 0; kt < 4; ++kt) {
        const int k0 = kt * 64;
        if constexpr (sizeof(AT) == 4) {           // fp32 A -> convert to f16
            #pragma unroll
            for (int p = 0; p < 4; ++p) {
                int idx = p * 512 + tid; int r = idx >> 4; int c4 = (idx & 15) * 4;
                const float4 v = *(const float4*)(A + (size_t)(row0 + r) * K + k0 + c4);
                half2_t h01; h01.x = (half_t)v.x; h01.y = (half_t)v.y;
                half2_t h23; h23.x = (half_t)v.z; h23.y = (half_t)v.w;
                *(half2_t*)&As[r][c4]     = h01;
                *(half2_t*)&As[r][c4 + 2] = h23;
            }
        } else {                                   // f16 A
            #pragma unroll
            for (int p = 0; p < 2; ++p) {
                int idx = p * 512 + tid; int r = idx >> 3; int c8 = (idx & 7) * 8;
                uint4 v = *(const uint4*)(A + (size_t)(row0 + r) * K + k0 + c8);
                *(uint4*)&As[r][c8] = v;
            }
        }
        #pragma unroll
        for (int p = 0; p < NT / 64; ++p) {        // stage W tile (f16)
            int idx = p * 512 + tid; int r = idx >> 3; int c8 = (idx & 7) * 8;
            uint4 v = *(const uint4*)(W + (size_t)r * K + k0 + c8);
            *(uint4*)&Ws[r][c8] = v;
        }
        __syncthreads();
        #pragma unroll
        for (int kkh = 0; kkh < 2; ++kkh) {
            const int kk = kkh * 32 + ((lane >> 4) * 8);
            f16x8 af[4], bf[NFRAG];
            #pragma unroll
            for (int m = 0; m < 4; ++m)
                af[m] = *(const f16x8*)&As[wr * 64 + m * 16 + (lane & 15)][kk];
            #pragma unroll
            for (int n = 0; n < NFRAG; ++n)
                bf[n] = *(const f16x8*)&Ws[wc * (NT / 4) + n * 16 + (lane & 15)][kk];
            #pragma unroll
            for (int m = 0; m < 4; ++m)
                #pragma unroll
                for (int n = 0; n < NFRAG; ++n)
                    acc[m][n] = __builtin_amdgcn_mfma_f32_16x16x32_f16(af[m], bf[n], acc[m][n], 0, 0, 0);
        }
        __syncthreads();
    }
    #pragma unroll
    for (int m = 0; m < 4; ++m)
        #pragma unroll
        for (int n = 0; n < NFRAG; ++n)
            #pragma unroll
            for (int jj = 0; jj < 4; ++jj) {
                int rl = wr * 64 + m * 16 + ((lane >> 4) * 4) + jj;
                int cl = wc * (NT / 4) + n * 16 + (lane & 15);
                float v = acc[m][n][jj] + bs[cl];
                if constexpr (SIG) v = 1.0f / (1.0f + __expf(-v));
                C[(size_t)(row0 + rl) * NT + cl] = (OT)v;
            }
}

// ---------------- fused 2-layer MFMA recurrent scan --------------------------
// 16 blocks x 256 threads (4 waves, 1/SIMD, 512-VGPR budget). Block owns 16
// batch rows. Per barrier-epoch e (0..500), with 1-step skew:
//   L0: h0(e)   = tanh_pre(Whh0.h0(e-1) + xp0(e))           [e < 500]
//   L1: h1(e-1) = tanh_pre(Wih1.h0(e-1) + Whh1.h1(e-2) + b1) [e > 0]
// h0(e-1) is the SHARED B-operand of Whh0-mm and Wih1-mm (one LDS read).
// Weights (pre-scaled by 2*log2e): j-slice 64 per wave, 384 VGPRs resident.
// b1 folded into acc init. h0 never goes to global; h1 streams out (8B/lane).
// Sync: s_barrier + counted s_waitcnt vmcnt(12) (6 vm ops/epoch in flight x2).

typedef __attribute__((address_space(1))) const unsigned gu32;
typedef __attribute__((address_space(3))) unsigned lu32;

__device__ __forceinline__ void stage16(const void* g, void* l) {
    __builtin_amdgcn_global_load_lds((gu32*)g, (lu32*)l, 16, 0, 0);
}

__device__ __forceinline__ int swz(int b, int byteoff) {
    return b * 512 + (byteoff ^ ((b & 7) << 4));
}

__device__ __forceinline__ float tanh_pre(float s) {
    // input pre-scaled by 2*log2(e): tanh = 1 - 2/(2^s + 1)
    float e = __builtin_amdgcn_exp2f(s);
    return __builtin_fmaf(-2.0f, __builtin_amdgcn_rcpf(e + 1.0f), 1.0f);
}

__global__ __launch_bounds__(256, 1) void rnn_fused_scan(
    const half_t* __restrict__ Whh0w,  // [256 j][256 k] f16, pre-scaled
    const half_t* __restrict__ Wih1w,  // [256 j][256 k] f16, pre-scaled
    const half_t* __restrict__ Whh1w,  // [256 j][256 k] f16, pre-scaled
    const float*  __restrict__ bias1,  // [256] f32, pre-scaled
    const half_t* __restrict__ xp0,    // [B*T][256] f16, pre-scaled + bias0
    half_t* __restrict__ h1out)        // [B*T][256] f16
{
    __shared__ __align__(16) char lds[65536];
    char* const h0t = lds;             // h0: 2 x 8192 B ping-pong, [16b][512B] swz
    char* const h1t = lds + 16384;     // h1: 2 x 8192 B ping-pong
    char* const xs  = lds + 32768;     // xp0: 4 x 8192 B rotating slots

    const int tid = threadIdx.x;
    const int w = tid >> 6, l = tid & 63, lq = l >> 4, bl = l & 15;
    const int blk = blockIdx.x;

    // resident weight frags: j = w*64 + m*16 + bl, k = kt*32 + lq*8 (+0..7)
    f16x8 wf0[4][8], wf1[4][8], wh1[4][8];
    #pragma unroll
    for (int m = 0; m < 4; ++m)
        #pragma unroll
        for (int kt = 0; kt < 8; ++kt) {
            const size_t o = (size_t)(w * 64 + m * 16 + bl) * 256 + kt * 32 + lq * 8;
            wf0[m][kt] = *(const f16x8*)(Whh0w + o);
            wf1[m][kt] = *(const f16x8*)(Wih1w + o);
            wh1[m][kt] = *(const f16x8*)(Whh1w + o);
        }
    // bias1 frags (j = w*64 + m*16 + lq*4 + jj), folded into acc1 init
    f32x4 b1f[4];
    #pragma unroll
    for (int m = 0; m < 4; ++m)
        b1f[m] = *(const f32x4*)(bias1 + w * 64 + m * 16 + lq * 4);

    // zero h0/h1 tiles (32 KB): h0(-1) = h1(-1) = h1(-2) = 0
    uint4 z = {0u, 0u, 0u, 0u};
    #pragma unroll
    for (int i = 0; i < 8; ++i) ((uint4*)lds)[i * 256 + tid] = z;

    // per-lane xp stage sources (pre-swizzled global addresses), rows 0-7 / 8-15
    const int r0 = tid >> 5, c0 = (tid & 31) * 16;
    const char* const srcA = (const char*)xp0
        + (size_t)(blk * 16 + r0) * 500 * 512 + (c0 ^ ((r0 & 7) << 4));
    const char* const srcB = (const char*)xp0
        + (size_t)(blk * 16 + 8 + r0) * 500 * 512 + (c0 ^ ((r0 & 7) << 4));

    // prologue: stage xp0(0..2) -> slots 0..2
    #pragma unroll
    for (int s = 0; s < 3; ++s) {
        stage16(srcA + (size_t)s * 512, xs + s * 8192 + w * 1024);
        stage16(srcB + (size_t)s * 512, xs + s * 8192 + 4096 + w * 1024);
    }

    // h1 global store cursor: element (blk*16+bl, t, w*64 + lq*4); starts at t=0
    char* hst = (char*)h1out + ((size_t)(blk * 16 + bl) * 500 * 256 + w * 64 + lq * 4) * 2;

    __syncthreads();   // one-time full drain: weights, zeros, slots 0..2 ready

    auto step = [&](int e, char* h0c, char* h0n, char* h1c, char* h1n,
                    bool doL0, bool doL1) {
        // prefetch xp0(e+3) (clamped source keeps vm-op count uniform)
        {
            const int tc = (e + 3 > 499) ? 499 : (e + 3);
            char* slot = xs + (size_t)((e + 3) & 3) * 8192;
            stage16(srcA + (size_t)tc * 512, slot + w * 1024);
            stage16(srcB + (size_t)tc * 512, slot + 4096 + w * 1024);
        }
        f32x4 acc0[4] = {};
        f32x4 acc1[4] = {b1f[0], b1f[1], b1f[2], b1f[3]};
        {   // shared B-operand h0(e-1): feeds Whh0 (acc0) and Wih1 (acc1)
            f16x8 bf0[8];
            #pragma unroll
            for (int kt = 0; kt < 8; ++kt)
                bf0[kt] = *(const f16x8*)(h0c + swz(bl, kt * 64 + lq * 16));
            #pragma unroll
            for (int kt = 0; kt < 8; ++kt)
                #pragma unroll
                for (int m = 0; m < 4; ++m) {
                    acc0[m] = __builtin_amdgcn_mfma_f32_16x16x32_f16(wf0[m][kt], bf0[kt], acc0[m], 0, 0, 0);
                    acc1[m] = __builtin_amdgcn_mfma_f32_16x16x32_f16(wf1[m][kt], bf0[kt], acc1[m], 0, 0, 0);
                }
        }
        {   // B-operand h1(e-2): feeds Whh1 (acc1)
            f16x8 bf1[8];
            #pragma unroll
            for (int kt = 0; kt < 8; ++kt)
                bf1[kt] = *(const f16x8*)(h1c + swz(bl, kt * 64 + lq * 16));
            #pragma unroll
            for (int kt = 0; kt < 8; ++kt)
                #pragma unroll
                for (int m = 0; m < 4; ++m)
                    acc1[m] = __builtin_amdgcn_mfma_f32_16x16x32_f16(wh1[m][kt], bf1[kt], acc1[m], 0, 0, 0);
        }
        if (doL0) {   // h0(e) = tanh_pre(acc0 + xp0(e)) -> LDS only
            const char* xcur = xs + (size_t)(e & 3) * 8192;
            #pragma unroll
            for (int m = 0; m < 4; ++m) {
                const int off = w * 128 + m * 32 + lq * 8;
                uint2 xv = *(const uint2*)(xcur + swz(bl, off));
                const half_t* xh = (const half_t*)&xv;
                float v0 = tanh_pre(acc0[m][0] + (float)xh[0]);
                float v1 = tanh_pre(acc0[m][1] + (float)xh[1]);
                float v2 = tanh_pre(acc0[m][2] + (float)xh[2]);
                float v3 = tanh_pre(acc0[m][3] + (float)xh[3]);
                uint2 hv;
                hv.x = __builtin_bit_cast(u32, __builtin_amdgcn_cvt_pkrtz(v0, v1));
                hv.y = __builtin_bit_cast(u32, __builtin_amdgcn_cvt_pkrtz(v2, v3));
                *(uint2*)(h0n + swz(bl, off)) = hv;
            }
        }
        if (doL1) {   // h1(e-1) = tanh_pre(acc1) -> LDS + global [b][t=e-1][j]
            #pragma unroll
            for (int m = 0; m < 4; ++m) {
                const int off = w * 128 + m * 32 + lq * 8;
                float v0 = tanh_pre(acc1[m][0]);
                float v1 = tanh_pre(acc1[m][1]);
                float v2 = tanh_pre(acc1[m][2]);
                float v3 = tanh_pre(acc1[m][3]);
                uint2 hv;
                hv.x = __builtin_bit_cast(u32, __builtin_amdgcn_cvt_pkrtz(v0, v1));
                hv.y = __builtin_bit_cast(u32, __builtin_amdgcn_cvt_pkrtz(v2, v3));
                *(uint2*)(h1n + swz(bl, off)) = hv;
                *(uint2*)(hst + m * 32) = hv;
            }
            hst += 512;
        }
        // counted wait: retire stage-pair needed by e+1 (>=16 ops issued after
        // it); keep 2 epochs of stores + 2 stage-pairs in flight. Then barrier.
        asm volatile("s_waitcnt vmcnt(12) lgkmcnt(0)\n\ts_barrier" ::: "memory");
    };

    // epoch 0: L0 only (h1 writes skipped; tiles stay zero = h1(-1))
    step(0, h0t, h0t + 8192, h1t, h1t + 8192, true, false);
    // epochs 1..498 (pairs)
    for (int i = 0; i < 249; ++i) {
        const int e = 2 * i + 1;
        step(e,     h0t + 8192, h0t, h1t + 8192, h1t, true, true);
        step(e + 1, h0t, h0t + 8192, h1t, h1t + 8192, true, true);
    }
    // epoch 499 (odd), epoch 500: L1 only (drain the skew)
    step(499, h0t + 8192, h0t, h1t + 8192, h1t, true, true);
    step(500, h0t, h0t + 8192, h1t, h1t + 8192, false, true);
}

// ---------------- launch ----------------
extern "C" void kernel_launch(void* const* d_in, const int* in_sizes, int n_in,
                              void* d_out, int out_size, void* d_ws, size_t ws_size,
                              hipStream_t stream) {
    const float* x    = (const float*)d_in[0];
    const float* Wih0 = (const float*)d_in[1];
    const float* Whh0 = (const float*)d_in[2];
    const float* bih0 = (const float*)d_in[3];
    const float* bhh0 = (const float*)d_in[4];
    const float* Wih1 = (const float*)d_in[5];
    const float* Whh1 = (const float*)d_in[6];
    const float* bih1 = (const float*)d_in[7];
    const float* bhh1 = (const float*)d_in[8];
    const float* fcW  = (const float*)d_in[9];
    const float* fcb  = (const float*)d_in[10];

    char* ws = (char*)d_ws;
    size_t off = 0;
    auto alloc = [&](size_t bytes) { void* p = ws + off; off += (bytes + 255) & ~(size_t)255; return p; };
    half_t* xp_buf = (half_t*)alloc((size_t)MROWS * 256 * 2);  // 65.5 MB
    half_t* h_buf  = (half_t*)alloc((size_t)MROWS * 256 * 2);  // 65.5 MB (h1)
    half_t* Wh0    = (half_t*)alloc(65536 * 2);
    half_t* Wh1    = (half_t*)alloc(65536 * 2);
    half_t* fcWh   = (half_t*)alloc(32768 * 2);
    half_t* Whh0h  = (half_t*)alloc(65536 * 2);
    half_t* Whh1h  = (half_t*)alloc(65536 * 2);
    float*  bias0  = (float*)alloc(256 * 4);
    float*  bias1  = (float*)alloc(256 * 4);
    float*  bias2  = (float*)alloc(128 * 4);

    prep_kernel<<<256, 256, 0, stream>>>(Wih0, Whh0, bih0, bhh0, Wih1, Whh1, bih1, bhh1,
                                         fcW, fcb, Wh0, Wh1, fcWh, Whh0h, Whh1h,
                                         bias0, bias1, bias2);
    // layer 0 input projection (fp32 x -> f16 xp0, bias folded, pre-scaled)
    gemm_bt<float, half_t, 256, false><<<1000, 512, 0, stream>>>(x, Wh0, bias0, xp_buf);
    // fused 2-layer scan (includes layer-1 input projection); writes h1
    rnn_fused_scan<<<16, 256, 0, stream>>>(Whh0h, Wh1, Whh1h, bias1, xp_buf, h_buf);
    // FC head + sigmoid -> fp32 out
    gemm_bt<half_t, float, 128, true><<<1000, 512, 0, stream>>>(h_buf, fcWh, bias2, (float*)d_out);
}

// Round 7
// 764.878 us; speedup vs baseline: 1.6014x; 1.6014x over previous
//
#include <hip/hip_runtime.h>
#include <hip/hip_fp16.h>

typedef _Float16 half_t;
typedef _Float16 half2_t __attribute__((ext_vector_type(2)));
typedef _Float16 f16x8 __attribute__((ext_vector_type(8)));
typedef float f32x4 __attribute__((ext_vector_type(4)));
typedef unsigned int u32;

// B=256, T=500, I=H=256, O=128, M=B*T=128000
#define MROWS 128000
#define KDIM 256
#define TANH_SCALE 2.8853900817779268f   // 2*log2(e): folded into Whh, Wih, biases

// ---------------- prep: convert weights to f16 layouts, fold biases ----------
__global__ __launch_bounds__(256) void prep_kernel(
    const float* __restrict__ Wih0, const float* __restrict__ Whh0,
    const float* __restrict__ bih0, const float* __restrict__ bhh0,
    const float* __restrict__ Wih1, const float* __restrict__ Whh1,
    const float* __restrict__ bih1, const float* __restrict__ bhh1,
    const float* __restrict__ fcW,  const float* __restrict__ fcb,
    half_t* __restrict__ Wh0, half_t* __restrict__ Wh1, half_t* __restrict__ fcWh,
    half_t* __restrict__ Whh0h, half_t* __restrict__ Whh1h,
    float* __restrict__ bias0, float* __restrict__ bias1, float* __restrict__ bias2)
{
    const float c = TANH_SCALE;
    int e = blockIdx.x * 256 + threadIdx.x;   // 0..65535
    Wh0[e] = (half_t)(Wih0[e] * c);           // scaled: xp0 arrives pre-multiplied
    Wh1[e] = (half_t)(Wih1[e] * c);           // scaled: used directly by fused scan
    Whh0h[e] = (half_t)(Whh0[e] * c);
    Whh1h[e] = (half_t)(Whh1[e] * c);
    if (e < 32768) fcWh[e] = (half_t)fcW[e];  // FC unscaled
    if (e < 256) { bias0[e] = (bih0[e] + bhh0[e]) * c; bias1[e] = (bih1[e] + bhh1[e]) * c; }
    if (e < 128) { bias2[e] = fcb[e]; }
}

// ---------------- GEMM: C[M,NT] = A[M,256] * W[NT,256]^T + bias (f16 MFMA) ---
template<typename AT, typename OT, int NT, bool SIG>
__global__ __launch_bounds__(512) void gemm_bt(
    const AT* __restrict__ A, const half_t* __restrict__ W,
    const float* __restrict__ bias, OT* __restrict__ C)
{
    constexpr int K = KDIM;
    __shared__ __align__(16) half_t As[128][72];   // +8 pad: 2-way bank alias only
    __shared__ __align__(16) half_t Ws[NT][72];
    __shared__ float bs[NT];
    const int tid  = threadIdx.x;
    const int row0 = blockIdx.x * 128;
    if (tid < NT) bs[tid] = bias[tid];
    constexpr int NFRAG = NT / 64;                 // 4 (NT=256) or 2 (NT=128)
    f32x4 acc[4][NFRAG] = {};
    const int lane = tid & 63;
    const int wid  = tid >> 6;                     // 8 waves: 2 (rows) x 4 (cols)
    const int wr = wid >> 2, wc = wid & 3;

    for (int kt = 0; kt < 4; ++kt) {
        const int k0 = kt * 64;
        if constexpr (sizeof(AT) == 4) {           // fp32 A -> convert to f16
            #pragma unroll
            for (int p = 0; p < 4; ++p) {
                int idx = p * 512 + tid; int r = idx >> 4; int c4 = (idx & 15) * 4;
                const float4 v = *(const float4*)(A + (size_t)(row0 + r) * K + k0 + c4);
                half2_t h01; h01.x = (half_t)v.x; h01.y = (half_t)v.y;
                half2_t h23; h23.x = (half_t)v.z; h23.y = (half_t)v.w;
                *(half2_t*)&As[r][c4]     = h01;
                *(half2_t*)&As[r][c4 + 2] = h23;
            }
        } else {                                   // f16 A
            #pragma unroll
            for (int p = 0; p < 2; ++p) {
                int idx = p * 512 + tid; int r = idx >> 3; int c8 = (idx & 7) * 8;
                uint4 v = *(const uint4*)(A + (size_t)(row0 + r) * K + k0 + c8);
                *(uint4*)&As[r][c8] = v;
            }
        }
        #pragma unroll
        for (int p = 0; p < NT / 64; ++p) {        // stage W tile (f16)
            int idx = p * 512 + tid; int r = idx >> 3; int c8 = (idx & 7) * 8;
            uint4 v = *(const uint4*)(W + (size_t)r * K + k0 + c8);
            *(uint4*)&Ws[r][c8] = v;
        }
        __syncthreads();
        #pragma unroll
        for (int kkh = 0; kkh < 2; ++kkh) {
            const int kk = kkh * 32 + ((lane >> 4) * 8);
            f16x8 af[4], bf[NFRAG];
            #pragma unroll
            for (int m = 0; m < 4; ++m)
                af[m] = *(const f16x8*)&As[wr * 64 + m * 16 + (lane & 15)][kk];
            #pragma unroll
            for (int n = 0; n < NFRAG; ++n)
                bf[n] = *(const f16x8*)&Ws[wc * (NT / 4) + n * 16 + (lane & 15)][kk];
            #pragma unroll
            for (int m = 0; m < 4; ++m)
                #pragma unroll
                for (int n = 0; n < NFRAG; ++n)
                    acc[m][n] = __builtin_amdgcn_mfma_f32_16x16x32_f16(af[m], bf[n], acc[m][n], 0, 0, 0);
        }
        __syncthreads();
    }
    #pragma unroll
    for (int m = 0; m < 4; ++m)
        #pragma unroll
        for (int n = 0; n < NFRAG; ++n)
            #pragma unroll
            for (int jj = 0; jj < 4; ++jj) {
                int rl = wr * 64 + m * 16 + ((lane >> 4) * 4) + jj;
                int cl = wc * (NT / 4) + n * 16 + (lane & 15);
                float v = acc[m][n][jj] + bs[cl];
                if constexpr (SIG) v = 1.0f / (1.0f + __expf(-v));
                C[(size_t)(row0 + rl) * NT + cl] = (OT)v;
            }
}

// ---------------- fused 2-layer MFMA recurrent scan --------------------------
// Grid 256 x 512 threads (8 waves, 2/SIMD, <=256 VGPR). Blocks 0..15 are LIVE
// (own batch-group blk = blockIdx & 15); blocks 16..255 are SHADOW/heater:
// identical compute for batch-group blk&15 but no global stores (keeps all
// 256 CUs busy -> no deep-idle clocks; xp duplicate reads are L3-served).
// Per barrier-epoch e (0..500), 1-step skew:
//   L0: h0(e)   = tanh_pre(Whh0.h0(e-1) + xp0(e))            [e < 500]
//   L1: h1(e-1) = tanh_pre(Wih1.h0(e-1) + Whh1.h1(e-2) + b1) [e > 0]
// h0(e-1) is the SHARED B-operand of the Whh0 and Wih1 MFMAs (one LDS read).
// Per wave: j-slice 32 -> weights 3 x 64 VGPR resident. b1 in acc init.
// xp: prefetch depth 4, 8 rotating LDS slots, global_load_lds (pre-swz src).
// Sync: s_barrier + counted vmcnt (live: 3 vm-ops/epoch, keep <=8; shadow: 1
// op/epoch, keep <=3). h0 never touches global; h1 streams out 8B/lane.

typedef __attribute__((address_space(1))) const unsigned gu32;
typedef __attribute__((address_space(3))) unsigned lu32;

__device__ __forceinline__ void stage16(const void* g, void* l) {
    __builtin_amdgcn_global_load_lds((gu32*)g, (lu32*)l, 16, 0, 0);
}

__device__ __forceinline__ int swz(int b, int byteoff) {
    return b * 512 + (byteoff ^ ((b & 7) << 4));
}

__device__ __forceinline__ float tanh_pre(float s) {
    // input pre-scaled by 2*log2(e): tanh = 1 - 2/(2^s + 1)
    float e = __builtin_amdgcn_exp2f(s);
    return __builtin_fmaf(-2.0f, __builtin_amdgcn_rcpf(e + 1.0f), 1.0f);
}

__global__ __launch_bounds__(512, 2) void rnn_fused_scan(
    const half_t* __restrict__ Whh0w,  // [256 j][256 k] f16, pre-scaled
    const half_t* __restrict__ Wih1w,  // [256 j][256 k] f16, pre-scaled
    const half_t* __restrict__ Whh1w,  // [256 j][256 k] f16, pre-scaled
    const float*  __restrict__ bias1,  // [256] f32, pre-scaled
    const half_t* __restrict__ xp0,    // [B*T][256] f16, pre-scaled + bias0
    half_t* __restrict__ h1out)        // [B*T][256] f16
{
    __shared__ __align__(16) char lds[98304];
    char* const h0t = lds;             // h0: 2 x 8192 B ping-pong, [16b][512B] swz
    char* const h1t = lds + 16384;     // h1: 2 x 8192 B ping-pong
    char* const xs  = lds + 32768;     // xp0: 8 x 8192 B rotating slots (64 KB)

    const int tid = threadIdx.x;
    const int w = tid >> 6, l = tid & 63, lq = l >> 4, bl = l & 15;
    const bool live = blockIdx.x < 16;
    const int blk = blockIdx.x & 15;

    // resident weight frags: j = w*32 + m*16 + bl, k = kt*32 + lq*8 (+0..7)
    f16x8 wf0[2][8], wf1[2][8], wh1[2][8];
    #pragma unroll
    for (int m = 0; m < 2; ++m)
        #pragma unroll
        for (int kt = 0; kt < 8; ++kt) {
            const size_t o = (size_t)(w * 32 + m * 16 + bl) * 256 + kt * 32 + lq * 8;
            wf0[m][kt] = *(const f16x8*)(Whh0w + o);
            wf1[m][kt] = *(const f16x8*)(Wih1w + o);
            wh1[m][kt] = *(const f16x8*)(Whh1w + o);
        }
    // bias1 frags (j = w*32 + m*16 + lq*4 + jj), folded into acc1 init
    f32x4 b1f[2];
    #pragma unroll
    for (int m = 0; m < 2; ++m)
        b1f[m] = *(const f32x4*)(bias1 + w * 32 + m * 16 + lq * 4);

    // zero h0/h1 tiles (32 KB): h0(-1) = h1(-1) = h1(-2) = 0
    uint4 z = {0u, 0u, 0u, 0u};
    #pragma unroll
    for (int i = 0; i < 4; ++i) ((uint4*)lds)[i * 512 + tid] = z;

    // per-lane xp stage source (pre-swizzled global address), at t=0
    const int r0 = tid >> 5, c0 = (tid & 31) * 16;   // r0: 0..15
    const char* const srcA = (const char*)xp0
        + (size_t)(blk * 16 + r0) * 500 * 512 + (c0 ^ ((r0 & 7) << 4));

    // prologue: stage xp0(0..3) -> slots 0..3 (1 stage16/wave covers 1 KB)
    #pragma unroll
    for (int s = 0; s < 4; ++s)
        stage16(srcA + (size_t)s * 512, xs + s * 8192 + w * 1024);

    // h1 global store cursor: element (blk*16+bl, t, w*32 + lq*4); starts t=0
    char* hst = (char*)h1out + ((size_t)(blk * 16 + bl) * 500 * 256 + w * 32 + lq * 4) * 2;

    __syncthreads();   // one-time full drain: weights, zeros, slots 0..3 ready

    auto step = [&](int e, char* h0c, char* h0n, char* h1c, char* h1n,
                    bool doL0, bool doL1) {
        // prefetch xp0(e+4) (clamped source keeps vm-op count uniform)
        {
            const int tc = (e + 4 > 499) ? 499 : (e + 4);
            stage16(srcA + (size_t)tc * 512, xs + (size_t)((e + 4) & 7) * 8192 + w * 1024);
        }
        f32x4 acc0[2] = {};
        f32x4 acc1[2] = {b1f[0], b1f[1]};
        {   // shared B-operand h0(e-1): feeds Whh0 (acc0) and Wih1 (acc1)
            f16x8 bf0[8];
            #pragma unroll
            for (int kt = 0; kt < 8; ++kt)
                bf0[kt] = *(const f16x8*)(h0c + swz(bl, kt * 64 + lq * 16));
            #pragma unroll
            for (int kt = 0; kt < 8; ++kt)
                #pragma unroll
                for (int m = 0; m < 2; ++m) {
                    acc0[m] = __builtin_amdgcn_mfma_f32_16x16x32_f16(wf0[m][kt], bf0[kt], acc0[m], 0, 0, 0);
                    acc1[m] = __builtin_amdgcn_mfma_f32_16x16x32_f16(wf1[m][kt], bf0[kt], acc1[m], 0, 0, 0);
                }
        }
        {   // B-operand h1(e-2): feeds Whh1 (acc1)
            f16x8 bf1[8];
            #pragma unroll
            for (int kt = 0; kt < 8; ++kt)
                bf1[kt] = *(const f16x8*)(h1c + swz(bl, kt * 64 + lq * 16));
            #pragma unroll
            for (int kt = 0; kt < 8; ++kt)
                #pragma unroll
                for (int m = 0; m < 2; ++m)
                    acc1[m] = __builtin_amdgcn_mfma_f32_16x16x32_f16(wh1[m][kt], bf1[kt], acc1[m], 0, 0, 0);
        }
        if (doL0) {   // h0(e) = tanh_pre(acc0 + xp0(e)) -> LDS only
            const char* xcur = xs + (size_t)(e & 7) * 8192;
            #pragma unroll
            for (int m = 0; m < 2; ++m) {
                const int off = w * 64 + m * 32 + lq * 8;
                uint2 xv = *(const uint2*)(xcur + swz(bl, off));
                const half_t* xh = (const half_t*)&xv;
                float v0 = tanh_pre(acc0[m][0] + (float)xh[0]);
                float v1 = tanh_pre(acc0[m][1] + (float)xh[1]);
                float v2 = tanh_pre(acc0[m][2] + (float)xh[2]);
                float v3 = tanh_pre(acc0[m][3] + (float)xh[3]);
                uint2 hv;
                hv.x = __builtin_bit_cast(u32, __builtin_amdgcn_cvt_pkrtz(v0, v1));
                hv.y = __builtin_bit_cast(u32, __builtin_amdgcn_cvt_pkrtz(v2, v3));
                *(uint2*)(h0n + swz(bl, off)) = hv;
            }
        }
        if (doL1) {   // h1(e-1) = tanh_pre(acc1) -> LDS + global [b][t=e-1][j]
            #pragma unroll
            for (int m = 0; m < 2; ++m) {
                const int off = w * 64 + m * 32 + lq * 8;
                float v0 = tanh_pre(acc1[m][0]);
                float v1 = tanh_pre(acc1[m][1]);
                float v2 = tanh_pre(acc1[m][2]);
                float v3 = tanh_pre(acc1[m][3]);
                uint2 hv;
                hv.x = __builtin_bit_cast(u32, __builtin_amdgcn_cvt_pkrtz(v0, v1));
                hv.y = __builtin_bit_cast(u32, __builtin_amdgcn_cvt_pkrtz(v2, v3));
                *(uint2*)(h1n + swz(bl, off)) = hv;
                if (live) *(uint2*)(hst + m * 32) = hv;
            }
            hst += 512;
        }
        // counted wait (block-uniform branch): retire the stage needed next
        // epoch; keep prefetches + recent stores in flight. Then barrier.
        if (live) asm volatile("s_waitcnt vmcnt(8) lgkmcnt(0)\n\ts_barrier" ::: "memory");
        else      asm volatile("s_waitcnt vmcnt(3) lgkmcnt(0)\n\ts_barrier" ::: "memory");
    };

    // epoch 0: L0 only (h1 tiles stay zero = h1(-1))
    step(0, h0t, h0t + 8192, h1t, h1t + 8192, true, false);
    // epochs 1..498 (pairs)
    for (int i = 0; i < 249; ++i) {
        const int e = 2 * i + 1;
        step(e,     h0t + 8192, h0t, h1t + 8192, h1t, true, true);
        step(e + 1, h0t, h0t + 8192, h1t, h1t + 8192, true, true);
    }
    // epoch 499 (odd), epoch 500: L1 only (drain the skew)
    step(499, h0t + 8192, h0t, h1t + 8192, h1t, true, true);
    step(500, h0t, h0t + 8192, h1t, h1t + 8192, false, true);
}

// ---------------- launch ----------------
extern "C" void kernel_launch(void* const* d_in, const int* in_sizes, int n_in,
                              void* d_out, int out_size, void* d_ws, size_t ws_size,
                              hipStream_t stream) {
    const float* x    = (const float*)d_in[0];
    const float* Wih0 = (const float*)d_in[1];
    const float* Whh0 = (const float*)d_in[2];
    const float* bih0 = (const float*)d_in[3];
    const float* bhh0 = (const float*)d_in[4];
    const float* Wih1 = (const float*)d_in[5];
    const float* Whh1 = (const float*)d_in[6];
    const float* bih1 = (const float*)d_in[7];
    const float* bhh1 = (const float*)d_in[8];
    const float* fcW  = (const float*)d_in[9];
    const float* fcb  = (const float*)d_in[10];

    char* ws = (char*)d_ws;
    size_t off = 0;
    auto alloc = [&](size_t bytes) { void* p = ws + off; off += (bytes + 255) & ~(size_t)255; return p; };
    half_t* xp_buf = (half_t*)alloc((size_t)MROWS * 256 * 2);  // 65.5 MB
    half_t* h_buf  = (half_t*)alloc((size_t)MROWS * 256 * 2);  // 65.5 MB (h1)
    half_t* Wh0    = (half_t*)alloc(65536 * 2);
    half_t* Wh1    = (half_t*)alloc(65536 * 2);
    half_t* fcWh   = (half_t*)alloc(32768 * 2);
    half_t* Whh0h  = (half_t*)alloc(65536 * 2);
    half_t* Whh1h  = (half_t*)alloc(65536 * 2);
    float*  bias0  = (float*)alloc(256 * 4);
    float*  bias1  = (float*)alloc(256 * 4);
    float*  bias2  = (float*)alloc(128 * 4);

    prep_kernel<<<256, 256, 0, stream>>>(Wih0, Whh0, bih0, bhh0, Wih1, Whh1, bih1, bhh1,
                                         fcW, fcb, Wh0, Wh1, fcWh, Whh0h, Whh1h,
                                         bias0, bias1, bias2);
    // layer 0 input projection (fp32 x -> f16 xp0, bias folded, pre-scaled)
    gemm_bt<float, half_t, 256, false><<<1000, 512, 0, stream>>>(x, Wh0, bias0, xp_buf);
    // fused 2-layer scan (includes layer-1 input projection); writes h1.
    // 16 live blocks + 240 heater/shadow blocks (identical compute, no stores)
    rnn_fused_scan<<<256, 512, 0, stream>>>(Whh0h, Wh1, Whh1h, bias1, xp_buf, h_buf);
    // FC head + sigmoid -> fp32 out
    gemm_bt<half_t, float, 128, true><<<1000, 512, 0, stream>>>(h_buf, fcWh, bias2, (float*)d_out);
}